// Round 19
// baseline (283.676 us; speedup 1.0000x reference)
//
#include <hip/hip_runtime.h>
#include <hip/hip_bf16.h>
#include <hip/hip_fp16.h>

#define B_  8192
#define D_  784
#define H_  2048
#define O_  1024
#define RH_ 128
#define P_  64
#define KP  224   // 196 padded to 7*32
#define KR  800   // router K: 784 padded to 25*32

typedef __attribute__((ext_vector_type(8))) short short8;
typedef __attribute__((ext_vector_type(8))) _Float16 h16x8;
typedef __attribute__((ext_vector_type(4))) float f32x4;

__device__ inline float bf2f(unsigned short u) {
  union { unsigned int i; float f; } v; v.i = ((unsigned int)u) << 16; return v.f;
}
__device__ inline unsigned short f2bf(float f) {
  __hip_bfloat16 h = __float2bfloat16(f);
  return *reinterpret_cast<unsigned short*>(&h);
}
__device__ inline unsigned short f2h(float f) {
  __half h = __float2half(f);
  return *reinterpret_cast<unsigned short*>(&h);
}
__device__ inline float h2f(unsigned short u) {
  __half h = *reinterpret_cast<__half*>(&u);
  return __half2float(h);
}
// Abramowitz-Stegun 7.1.26, max abs err ~1.5e-7
__device__ inline float erf_fast(float x) {
  float ax = fabsf(x);
  float t = 1.0f / (1.0f + 0.3275911f * ax);
  float p = ((((1.061405429f * t - 1.453152027f) * t + 1.421413741f) * t
              - 0.284496736f) * t + 0.254829592f) * t;
  float y = 1.0f - p * __expf(-ax * ax);
  return x < 0.f ? -y : y;
}
__device__ inline float gelu_exact(float v) {
  return 0.5f * v * (1.0f + erf_fast(v * 0.70710678118654752f));
}

__device__ inline void gload_lds16(const void* g, void* l) {
  __builtin_amdgcn_global_load_lds((const __attribute__((address_space(1))) void*)g,
                                   (__attribute__((address_space(3))) void*)l, 16, 0, 0);
}

// 128x128xK MFMA tile, double-buffered, counted-vmcnt (T4). 32KB LDS.
// T2 source-preswizzle (conflict-free, verified R3-R18: SQ_LDS_BANK_CONFLICT==0).
template <bool F16>
__device__ inline void gemm128_db(const unsigned short* gA0, const unsigned short* gA1,
                                  const unsigned short* gB0, const unsigned short* gB1,
                                  int K, char* lds, f32x4 acc[4][4]) {
  const int t = threadIdx.x;
  const int w = t >> 6, l = t & 63;
  const int wr = (w >> 1) * 64, wc = (w & 1) * 64;
  const int lr = l & 15;
  const int swr = (lr >> 1) & 3;
  const int arow = (wr + lr) * 64 + (((l >> 4) ^ swr) * 16);
  const int brow = 8192 + (wc + lr) * 64 + (((l >> 4) ^ swr) * 16);
  const int tOff = t * 16;
  {
    char* d = lds + tOff;
    gload_lds16(gA0, d);
    gload_lds16(gA1, d + 4096);
    gload_lds16(gB0, d + 8192);
    gload_lds16(gB1, d + 12288);
  }
  int cur = 0;
  for (int kt = 0; kt < K; kt += 32) {
    const int nxt = kt + 32;
    if (nxt < K) {
      char* d = lds + ((cur ^ 1) << 14) + tOff;
      gload_lds16(gA0 + nxt, d);
      gload_lds16(gA1 + nxt, d + 4096);
      gload_lds16(gB0 + nxt, d + 8192);
      gload_lds16(gB1 + nxt, d + 12288);
      __builtin_amdgcn_sched_barrier(0);
      asm volatile("s_waitcnt vmcnt(4)" ::: "memory");
    } else {
      __builtin_amdgcn_sched_barrier(0);
      asm volatile("s_waitcnt vmcnt(0)" ::: "memory");
    }
    __builtin_amdgcn_sched_barrier(0);
    __builtin_amdgcn_s_barrier();
    __builtin_amdgcn_sched_barrier(0);
    const char* buf = lds + (cur << 14);
    short8 af[4], bfr[4];
#pragma unroll
    for (int f = 0; f < 4; ++f) {
      af[f]  = *(const short8*)(buf + arow + f * 1024);
      bfr[f] = *(const short8*)(buf + brow + f * 1024);
    }
#pragma unroll
    for (int fm = 0; fm < 4; ++fm)
#pragma unroll
      for (int fn = 0; fn < 4; ++fn) {
        if constexpr (F16)
          acc[fm][fn] = __builtin_amdgcn_mfma_f32_16x16x32_f16(
              (h16x8)af[fm], (h16x8)bfr[fn], acc[fm][fn], 0, 0, 0);
        else
          acc[fm][fn] = __builtin_amdgcn_mfma_f32_16x16x32_bf16(af[fm], bfr[fn], acc[fm][fn], 0, 0, 0);
      }
    __builtin_amdgcn_sched_barrier(0);
    __builtin_amdgcn_s_barrier();
    __builtin_amdgcn_sched_barrier(0);
    cur ^= 1;
  }
}

// BK=64 variant, counted vmcnt(8). 64KB LDS. (R14-best for l2.)
__device__ inline void gemm128_db64(const unsigned short* gA0, const unsigned short* gA1,
                                    const unsigned short* gB0, const unsigned short* gB1,
                                    int K, char* lds, f32x4 acc[4][4]) {
  const int t = threadIdx.x;
  const int w = t >> 6, l = t & 63;
  const int wr = (w >> 1) * 64, wc = (w & 1) * 64;
  const int lr = l & 15;
  const int swr = (lr >> 1) & 3;
  const int arow = (wr + lr) * 64 + (((l >> 4) ^ swr) * 16);
  const int brow = 8192 + (wc + lr) * 64 + (((l >> 4) ^ swr) * 16);
  const int tOff = t * 16;
#define STAGE64(bufbase, ksrc) { \
    char* d = lds + (bufbase) + tOff; \
    gload_lds16(gA0 + (ksrc), d); \
    gload_lds16(gA1 + (ksrc), d + 4096); \
    gload_lds16(gB0 + (ksrc), d + 8192); \
    gload_lds16(gB1 + (ksrc), d + 12288); \
    gload_lds16(gA0 + (ksrc) + 32, d + 16384); \
    gload_lds16(gA1 + (ksrc) + 32, d + 16384 + 4096); \
    gload_lds16(gB0 + (ksrc) + 32, d + 16384 + 8192); \
    gload_lds16(gB1 + (ksrc) + 32, d + 16384 + 12288); \
  }
  STAGE64(0, 0);
  int cur = 0;
  for (int kt = 0; kt < K; kt += 64) {
    if (kt + 64 < K) {
      STAGE64((cur ^ 1) << 15, kt + 64);
      __builtin_amdgcn_sched_barrier(0);
      asm volatile("s_waitcnt vmcnt(8)" ::: "memory");
    } else {
      __builtin_amdgcn_sched_barrier(0);
      asm volatile("s_waitcnt vmcnt(0)" ::: "memory");
    }
    __builtin_amdgcn_sched_barrier(0);
    __builtin_amdgcn_s_barrier();
    __builtin_amdgcn_sched_barrier(0);
    const char* buf = lds + (cur << 15);
#pragma unroll
    for (int c = 0; c < 2; ++c) {
      const char* ch = buf + c * 16384;
      short8 af[4], bfr[4];
#pragma unroll
      for (int f = 0; f < 4; ++f) {
        af[f]  = *(const short8*)(ch + arow + f * 1024);
        bfr[f] = *(const short8*)(ch + brow + f * 1024);
      }
#pragma unroll
      for (int fm = 0; fm < 4; ++fm)
#pragma unroll
        for (int fn = 0; fn < 4; ++fn)
          acc[fm][fn] = __builtin_amdgcn_mfma_f32_16x16x32_bf16(af[fm], bfr[fn], acc[fm][fn], 0, 0, 0);
    }
    __builtin_amdgcn_sched_barrier(0);
    __builtin_amdgcn_s_barrier();
    __builtin_amdgcn_sched_barrier(0);
    cur ^= 1;
  }
#undef STAGE64
}

__device__ inline void gemm128_bt64(const unsigned short* __restrict__ A,
                                    const unsigned short* __restrict__ Bm,
                                    int K, char* lds, f32x4 acc[4][4]) {
  const int t = threadIdx.x;
  const int s_orig = (t & 3) ^ ((t >> 3) & 3);
  const size_t srcOff = (size_t)(t >> 2) * K + s_orig * 8;
  gemm128_db64(A + srcOff, A + srcOff + (size_t)64 * K,
               Bm + srcOff, Bm + srcOff + (size_t)64 * K, K, lds, acc);
}

// ---- prep: gather/pad/convert x_reg, W1g; W2 bf16; router fp16 hi/lo splits ----
__global__ void k_prep(const float* __restrict__ x, const float* __restrict__ W1,
                       const float* __restrict__ W2, const int* __restrict__ ig,
                       const float* __restrict__ Wr1,
                       unsigned short* __restrict__ xreg, unsigned short* __restrict__ w1g,
                       unsigned short* __restrict__ w2b,
                       unsigned short* __restrict__ xsp, unsigned short* __restrict__ wr1sp) {
  const size_t N1 = (size_t)4 * B_ * KP;
  const size_t N2 = (size_t)4 * H_ * KP;
  const size_t N3 = (size_t)O_ * H_;
  const size_t N4 = (size_t)B_ * KR;
  const size_t N5 = (size_t)RH_ * KR;
  const size_t TOT = N1 + N2 + N3 + N4 + N5;
  for (size_t idx = (size_t)blockIdx.x * blockDim.x + threadIdx.x; idx < TOT;
       idx += (size_t)gridDim.x * blockDim.x) {
    if (idx < N1) {
      int n = (int)(idx % KP); size_t r = idx / KP;
      int b = (int)(r % B_); int i = (int)(r / B_);
      float v = (n < 196) ? x[(size_t)b * D_ + ig[i * 196 + n]] : 0.f;
      xreg[idx] = f2bf(v);
    } else if (idx < N1 + N2) {
      size_t q = idx - N1;
      int n = (int)(q % KP); size_t r = q / KP;
      int h = (int)(r % H_); int i = (int)(r / H_);
      float v = (n < 196) ? W1[(size_t)h * D_ + ig[i * 196 + n]] : 0.f;
      w1g[q] = f2bf(v);
    } else if (idx < N1 + N2 + N3) {
      size_t q = idx - N1 - N2;
      w2b[q] = f2bf(W2[q]);
    } else if (idx < N1 + N2 + N3 + N4) {
      size_t q = idx - N1 - N2 - N3;
      int c = (int)(q % KR); int b = (int)(q / KR);
      float v = (c < D_) ? x[(size_t)b * D_ + c] : 0.f;
      unsigned short hi = f2h(v);
      unsigned short lo = f2h(v - h2f(hi));
      xsp[(size_t)b * (2 * KR) + c]      = hi;
      xsp[(size_t)b * (2 * KR) + KR + c] = lo;
    } else {
      size_t q = idx - N1 - N2 - N3 - N4;
      int c = (int)(q % KR); int h = (int)(q / KR);
      float v = (c < D_) ? Wr1[(size_t)h * D_ + c] : 0.f;
      unsigned short hi = f2h(v);
      unsigned short lo = f2h(v - h2f(hi));
      wr1sp[(size_t)h * KR + c]                    = hi;  // term 0: hi (vs x_hi)
      wr1sp[(size_t)RH_ * KR + h * KR + c]         = hi;  // term 1: hi (vs x_lo)
      wr1sp[(size_t)2 * RH_ * KR + h * KR + c]     = lo;  // term 2: lo (vs x_hi)
    }
  }
}

// ---- router stage 1: fp16x3 MFMA GEMM. hrp[z][b][h], z = term. grid (64,3) ----
__global__ __launch_bounds__(256) void k_r1m(const unsigned short* __restrict__ xsp,
    const unsigned short* __restrict__ wr1sp, float* __restrict__ hrp) {
  __shared__ __align__(128) char lds[32768];
  const int mt = blockIdx.x, z = blockIdx.y;
  const int t = threadIdx.x;
  const int aoff = (z == 1) ? KR : 0;
  const int s_orig = (t & 3) ^ ((t >> 3) & 3);
  const int scol = s_orig * 8;
  const unsigned short* gA0 = xsp + ((size_t)(mt * 128) + (t >> 2)) * (2 * KR) + aoff + scol;
  const unsigned short* gA1 = gA0 + (size_t)64 * (2 * KR);
  const unsigned short* gB0 = wr1sp + (size_t)z * RH_ * KR + (size_t)(t >> 2) * KR + scol;
  const unsigned short* gB1 = gB0 + (size_t)64 * KR;
  f32x4 acc[4][4];
#pragma unroll
  for (int a = 0; a < 4; ++a)
#pragma unroll
    for (int b = 0; b < 4; ++b) acc[a][b] = (f32x4){0.f, 0.f, 0.f, 0.f};
  gemm128_db<true>(gA0, gA1, gB0, gB1, KR, lds, acc);
  float* hz = hrp + (size_t)z * B_ * RH_;
  const int w = t >> 6, l = t & 63;
  const int rbase = mt * 128 + (w >> 1) * 64 + (l >> 4) * 4;
  const int cb = (w & 1) * 64 + (l & 15);
#pragma unroll
  for (int fn = 0; fn < 4; ++fn) {
    const int h = cb + fn * 16;
#pragma unroll
    for (int fm = 0; fm < 4; ++fm)
#pragma unroll
      for (int r = 0; r < 4; ++r)
        hz[(size_t)(rbase + fm * 16 + r) * RH_ + h] = acc[fm][fn][r];
  }
}

// ---- router stage 2: reduce partials + bias + relu, softmax, top-8, weights;
// APPENDS active samples to per-(i,j) lists via atomicAdd. List ORDER is
// nondeterministic but no output value depends on it (l1g values depend only
// on row content; pad rows are never stored). counts zeroed by memset. ----
#define R2S 32
__global__ __launch_bounds__(256) void k_r2(const float* __restrict__ hrp,
    const float* __restrict__ br1,
    const float* __restrict__ Wr2, const float* __restrict__ br2,
    float* __restrict__ wts, float* __restrict__ wsum,
    int* __restrict__ lists, int* __restrict__ counts) {
  __shared__ float Ws[64][130];
  __shared__ float hs[R2S][128];
  const int s0 = blockIdx.x * R2S;
  const int t = threadIdx.x;
  for (int idx = t; idx < 2048; idx += 256) {
    int r = idx >> 5, c = (idx & 31) * 4;
    *(float4*)&Ws[r][c] = *(const float4*)(Wr2 + (size_t)r * RH_ + c);
  }
  for (int idx = t; idx < R2S * 32; idx += 256) {
    int r = idx >> 5, c = (idx & 31) * 4;
    const size_t off = (size_t)(s0 + r) * RH_ + c;
    float4 p0 = *(const float4*)(hrp + off);
    float4 p1 = *(const float4*)(hrp + (size_t)1 * B_ * RH_ + off);
    float4 p2 = *(const float4*)(hrp + (size_t)2 * B_ * RH_ + off);
    float4 bb = *(const float4*)(br1 + c);
    float4 s;
    s.x = fmaxf(p0.x + p1.x + p2.x + bb.x, 0.f);
    s.y = fmaxf(p0.y + p1.y + p2.y + bb.y, 0.f);
    s.z = fmaxf(p0.z + p1.z + p2.z + bb.z, 0.f);
    s.w = fmaxf(p0.w + p1.w + p2.w + bb.w, 0.f);
    *(float4*)&hs[r][c] = s;
  }
  __syncthreads();
  const int w = t >> 6, p = t & 63;
  const float wb2 = br2[p];
  for (int si = 0; si < R2S / 4; ++si) {
    const int sl = w * (R2S / 4) + si;
    float sc = wb2;
#pragma unroll
    for (int kk = 0; kk < 32; ++kk) {
      float4 h4 = *(const float4*)&hs[sl][kk * 4];
      float4 w4 = *(const float4*)&Ws[p][kk * 4];
      sc += h4.x * w4.x + h4.y * w4.y + h4.z * w4.z + h4.w * w4.w;
    }
    float m = sc;
#pragma unroll
    for (int o = 32; o; o >>= 1) m = fmaxf(m, __shfl_xor(m, o));
    float e = __expf(sc - m);
    float Z = e;
#pragma unroll
    for (int o = 32; o; o >>= 1) Z += __shfl_xor(Z, o);
    bool sel = false;
    float ssum = 0.f;
    for (int it = 0; it < 8; ++it) {
      float v = sel ? -1.f : e;
      float vm = v;
#pragma unroll
      for (int o = 32; o; o >>= 1) vm = fmaxf(vm, __shfl_xor(vm, o));
      unsigned long long mask = __ballot(!sel && v == vm);
      int first = __ffsll((long long)mask) - 1;
      if (p == first) sel = true;
      ssum += vm;
    }
    const float dn = 1.0f / (ssum + 1e-8f * Z);
    const float wv = sel ? e * dn : 0.f;
    wts[(size_t)(s0 + sl) * 64 + p] = wv;
    const unsigned long long am = __ballot(sel);
    if (p < 16) {                       // lane p handles pathway-group ij = p
      if ((am >> (p * 4)) & 0xFULL) {
        int pos = atomicAdd(&counts[p], 1);
        lists[p * B_ + pos] = s0 + sl;
      }
    }
    float part = wv;
#pragma unroll
    for (int o = 4; o < 64; o <<= 1) part += __shfl_xor(part, o);
    if (p < 4) wsum[(size_t)(s0 + sl) * 4 + p] = part;
  }
}

// ---- layer 1, ONE-SHOT FULL-K STAGE: 112KB LDS holds the entire A (gathered
// 128 rows x 224) and B (128 x 224) tiles; single vmcnt(0)+barrier; then all
// 112 MFMA with NO further barriers (data read-only). Latency exposed once
// per block instead of 7x (R18 diagnosis: per-step latency at ~2 blocks/CU).
// XCD-clustered mapping kept (L2-resident loads). fp16 pre-act out. ----
__global__ __launch_bounds__(256) void k_l1g(const unsigned short* __restrict__ xreg,
    const unsigned short* __restrict__ w1g, const float* __restrict__ b1,
    const int* __restrict__ lists, const int* __restrict__ counts,
    unsigned short* __restrict__ hid16) {
  const int id = blockIdx.x;
  const int xcd = id & 7;
  const int within = id >> 3;          // 0..511
  const int ij = xcd * 2 + (within >> 8);
  const int sub = within & 255;
  const int mt = sub >> 2;
  const int ntl = sub & 3;
  const int iq = ij >> 2;
  const int nt = (ij & 3) * 4 + ntl;
  const int count = counts[ij];
  if (mt * 128 >= count) return;
  __shared__ __align__(128) char lds[114688];   // A 7*8KB | B 7*8KB
  __shared__ int rows[128];
  const int t = threadIdx.x;
  const int* list = lists + (size_t)ij * B_;
  if (t < 128) {
    int rl = mt * 128 + t;
    rows[t] = list[rl < count ? rl : count - 1];
  }
  __syncthreads();
  const int s_orig = (t & 3) ^ ((t >> 3) & 3);
  const int scol = s_orig * 8;
  const int r0 = rows[t >> 2], r1 = rows[(t >> 2) + 64];
  const unsigned short* gA0 = xreg + ((size_t)iq * B_ + r0) * KP + scol;
  const unsigned short* gA1 = xreg + ((size_t)iq * B_ + r1) * KP + scol;
  const unsigned short* gB0 = w1g + ((size_t)(iq * H_ + nt * 128) + (t >> 2)) * KP + scol;
  const unsigned short* gB1 = gB0 + (size_t)64 * KP;
  char* ldsA = lds;
  char* ldsB = lds + 57344;
  const int tOff = t * 16;
#pragma unroll
  for (int ks = 0; ks < 7; ++ks) {
    gload_lds16(gA0 + ks * 32, ldsA + ks * 8192 + tOff);
    gload_lds16(gA1 + ks * 32, ldsA + ks * 8192 + 4096 + tOff);
    gload_lds16(gB0 + ks * 32, ldsB + ks * 8192 + tOff);
    gload_lds16(gB1 + ks * 32, ldsB + ks * 8192 + 4096 + tOff);
  }
  asm volatile("s_waitcnt vmcnt(0)" ::: "memory");
  __builtin_amdgcn_sched_barrier(0);
  __builtin_amdgcn_s_barrier();
  __builtin_amdgcn_sched_barrier(0);
  const int w = t >> 6, l = t & 63;
  const int wr = (w >> 1) * 64, wc = (w & 1) * 64;
  const int lr = l & 15;
  const int swr = (lr >> 1) & 3;
  const int arow = (wr + lr) * 64 + (((l >> 4) ^ swr) * 16);
  const int brow = (wc + lr) * 64 + (((l >> 4) ^ swr) * 16);
  f32x4 acc[4][4];
#pragma unroll
  for (int a = 0; a < 4; ++a)
#pragma unroll
    for (int b = 0; b < 4; ++b) acc[a][b] = (f32x4){0.f, 0.f, 0.f, 0.f};
#pragma unroll
  for (int ks = 0; ks < 7; ++ks) {
    const char* bufA = ldsA + ks * 8192;
    const char* bufB = ldsB + ks * 8192;
    short8 af[4], bfr[4];
#pragma unroll
    for (int f = 0; f < 4; ++f) {
      af[f]  = *(const short8*)(bufA + arow + f * 1024);
      bfr[f] = *(const short8*)(bufB + brow + f * 1024);
    }
#pragma unroll
    for (int fm = 0; fm < 4; ++fm)
#pragma unroll
      for (int fn = 0; fn < 4; ++fn)
        acc[fm][fn] = __builtin_amdgcn_mfma_f32_16x16x32_bf16(af[fm], bfr[fn], acc[fm][fn], 0, 0, 0);
  }
  // epilogue: bias + fp16 pre-act -> LDS repack (16B-granule XOR swizzle) -> vector scatter
  const int rloc0 = (w >> 1) * 64 + (l >> 4) * 4;
  const int cloc = (w & 1) * 64 + (l & 15);
  unsigned short* lt = (unsigned short*)lds;
  __syncthreads();   // all LDS reads done before overwrite
#pragma unroll
  for (int fn = 0; fn < 4; ++fn) {
    const int col = cloc + fn * 16;
    const float bias = b1[nt * 128 + col];
#pragma unroll
    for (int fm = 0; fm < 4; ++fm)
#pragma unroll
      for (int r = 0; r < 4; ++r) {
        const int row = rloc0 + fm * 16 + r;
        const int gsw = (col >> 3) ^ (row & 7);
        lt[row * 128 + gsw * 8 + (col & 7)] = f2h(acc[fm][fn][r] + bias);
      }
  }
  __syncthreads();
  const int mlim = count - mt * 128;
  const int row = t >> 1, half = t & 1;
  if (row < mlim) {
    unsigned short* dst = hid16 + ((size_t)iq * B_ + rows[row]) * H_ + nt * 128 + half * 64;
#pragma unroll
    for (int q = 0; q < 8; ++q) {
      const int g = (half * 8 + q) ^ (row & 7);
      *(short8*)(dst + q * 8) = *(const short8*)(lt + row * 128 + g * 8);
    }
  }
}

// ---- combine: skip zero-weight pathways, gelu here (idle VALU). fp16 -> bf16 G ----
__global__ __launch_bounds__(256) void k_combine(unsigned short* __restrict__ hid,
                                                 const float* __restrict__ wts) {
  const int b = blockIdx.x;
  const int n = threadIdx.x * 8;
  const int j = n >> 9;
  const float* wb = wts + (size_t)b * 64 + j * 4;
  float acc[4][8];
#pragma unroll
  for (int k = 0; k < 4; ++k)
#pragma unroll
    for (int e = 0; e < 8; ++e) acc[k][e] = 0.f;
#pragma unroll
  for (int i = 0; i < 4; ++i) {
    const float4 w4 = *(const float4*)(wb + i * 16);
    if (w4.x != 0.f || w4.y != 0.f || w4.z != 0.f || w4.w != 0.f) {
      short8 raw = *(const short8*)(hid + ((size_t)i * B_ + b) * H_ + n);
#pragma unroll
      for (int e = 0; e < 8; ++e) {
        float g = gelu_exact(h2f((unsigned short)raw[e]));
        acc[0][e] += g * w4.x;
        acc[1][e] += g * w4.y;
        acc[2][e] += g * w4.z;
        acc[3][e] += g * w4.w;
      }
    }
  }
#pragma unroll
  for (int k = 0; k < 4; ++k) {
    short8 outv;
#pragma unroll
    for (int e = 0; e < 8; ++e) outv[e] = (short)f2bf(acc[k][e]);
    *(short8*)(hid + ((size_t)k * B_ + b) * H_ + n) = outv;
  }
}

// ---- layer 2 (R14-best config): BK=64, 64KB LDS, id>>6 panel grouping. ----
__global__ __launch_bounds__(256) void k_l2(const unsigned short* __restrict__ G,
    const unsigned short* __restrict__ w2b, const float* __restrict__ b2,
    const float* __restrict__ wsum, float* __restrict__ out) {
  __shared__ __align__(128) char lds[65536];
  const int id = blockIdx.x;
  const int grp = id >> 6, mt = id & 63;
  const int nt = grp & 1, k = grp >> 1;
  const unsigned short* A  = G + ((size_t)k * B_ + mt * 128) * H_;
  const unsigned short* Bm = w2b + ((size_t)(k * 256 + nt * 128)) * H_;
  f32x4 acc[4][4];
#pragma unroll
  for (int a = 0; a < 4; ++a)
#pragma unroll
    for (int b = 0; b < 4; ++b) acc[a][b] = (f32x4){0.f, 0.f, 0.f, 0.f};
  gemm128_bt64(A, Bm, H_, lds, acc);
  const int t = threadIdx.x, w = t >> 6, l = t & 63;
  const int rbase = mt * 128 + (w >> 1) * 64 + (l >> 4) * 4;
  const int cb = nt * 128 + (w & 1) * 64 + (l & 15);
#pragma unroll
  for (int fn = 0; fn < 4; ++fn) {
    const int ncol = k * 256 + cb + fn * 16;
    const float bias = b2[ncol];
#pragma unroll
    for (int fm = 0; fm < 4; ++fm)
#pragma unroll
      for (int r = 0; r < 4; ++r) {
        const int m = rbase + fm * 16 + r;
        out[(size_t)m * O_ + ncol] = acc[fm][fn][r] + wsum[m * 4 + k] * bias;
      }
  }
}

extern "C" void kernel_launch(void* const* d_in, const int* in_sizes, int n_in,
                              void* d_out, int out_size, void* d_ws, size_t ws_size,
                              hipStream_t stream) {
  const float* x   = (const float*)d_in[0];
  const float* W1  = (const float*)d_in[1];
  const float* b1  = (const float*)d_in[2];
  const float* W2  = (const float*)d_in[3];
  const float* b2  = (const float*)d_in[4];
  const float* Wr1 = (const float*)d_in[5];
  const float* br1 = (const float*)d_in[6];
  const float* Wr2 = (const float*)d_in[7];
  const float* br2 = (const float*)d_in[8];
  const int*   ig  = (const int*)d_in[9];
  float* out = (float*)d_out;
  char* ws = (char*)d_ws;
  unsigned short* xreg = (unsigned short*)(ws);              // 14,680,064 B
  unsigned short* w1g  = (unsigned short*)(ws + 14680064);   //  3,670,016 B
  unsigned short* w2b  = (unsigned short*)(ws + 18350080);   //  4,194,304 B
  float*          wts  = (float*)(ws + 22544384);            //  2,097,152 B
  float*          wsum = (float*)(ws + 24641536);            //    131,072 B
  unsigned short* hid  = (unsigned short*)(ws + 24772608);   // 134,217,728 B (fp16 pre-act, then bf16 G in-place)
  // router-phase scratch aliased onto hid region (all dead before k_l1g writes):
  float*          hrp   = (float*)(ws + 24772608);                 // 12,582,912 B
  unsigned short* xsp   = (unsigned short*)(ws + 24772608 + 12582912);   // 26,214,400 B
  unsigned short* wr1sp = (unsigned short*)(ws + 24772608 + 38797312);   // 614,400 B
  // scratch in d_out (fully overwritten by k_l2's dense writes afterwards):
  int*                lists   = (int*)d_out;                 // 524,288 B
  int*                counts  = lists + 16 * B_;             // 64 B

  k_prep<<<dim3(2048), dim3(256), 0, stream>>>(x, W1, W2, ig, Wr1, xreg, w1g, w2b, xsp, wr1sp);
  hipMemsetAsync(counts, 0, 64, stream);
  k_r1m<<<dim3(B_ / 128, 3), dim3(256), 0, stream>>>(xsp, wr1sp, hrp);
  k_r2<<<dim3(B_ / R2S), dim3(256), 0, stream>>>(hrp, br1, Wr2, br2, wts, wsum, lists, counts);
  k_l1g<<<dim3(4096), dim3(256), 0, stream>>>(xreg, w1g, b1, lists, counts, hid);
  k_combine<<<dim3(B_), dim3(256), 0, stream>>>(hid, wts);
  k_l2<<<dim3(512), dim3(256), 0, stream>>>(hid, w2b, b2, wsum, out);
}

// Round 20
// 219.676 us; speedup vs baseline: 1.2913x; 1.2913x over previous
//
#include <hip/hip_runtime.h>
#include <hip/hip_bf16.h>
#include <hip/hip_fp16.h>

#define B_  8192
#define D_  784
#define H_  2048
#define O_  1024
#define RH_ 128
#define P_  64
#define KP  224   // 196 padded to 7*32
#define KR  800   // router K: 784 padded to 25*32

typedef __attribute__((ext_vector_type(8))) short short8;
typedef __attribute__((ext_vector_type(8))) _Float16 h16x8;
typedef __attribute__((ext_vector_type(4))) float f32x4;

__device__ inline float bf2f(unsigned short u) {
  union { unsigned int i; float f; } v; v.i = ((unsigned int)u) << 16; return v.f;
}
__device__ inline unsigned short f2bf(float f) {
  __hip_bfloat16 h = __float2bfloat16(f);
  return *reinterpret_cast<unsigned short*>(&h);
}
__device__ inline unsigned short f2h(float f) {
  __half h = __float2half(f);
  return *reinterpret_cast<unsigned short*>(&h);
}
__device__ inline float h2f(unsigned short u) {
  __half h = *reinterpret_cast<__half*>(&u);
  return __half2float(h);
}
// Abramowitz-Stegun 7.1.26, max abs err ~1.5e-7
__device__ inline float erf_fast(float x) {
  float ax = fabsf(x);
  float t = 1.0f / (1.0f + 0.3275911f * ax);
  float p = ((((1.061405429f * t - 1.453152027f) * t + 1.421413741f) * t
              - 0.284496736f) * t + 0.254829592f) * t;
  float y = 1.0f - p * __expf(-ax * ax);
  return x < 0.f ? -y : y;
}
__device__ inline float gelu_exact(float v) {
  return 0.5f * v * (1.0f + erf_fast(v * 0.70710678118654752f));
}

__device__ inline void gload_lds16(const void* g, void* l) {
  __builtin_amdgcn_global_load_lds((const __attribute__((address_space(1))) void*)g,
                                   (__attribute__((address_space(3))) void*)l, 16, 0, 0);
}

// 128x128xK MFMA tile, double-buffered, counted-vmcnt (T4). 32KB LDS.
// T2 source-preswizzle (conflict-free, verified R3-R19: SQ_LDS_BANK_CONFLICT==0).
template <bool F16>
__device__ inline void gemm128_db(const unsigned short* gA0, const unsigned short* gA1,
                                  const unsigned short* gB0, const unsigned short* gB1,
                                  int K, char* lds, f32x4 acc[4][4]) {
  const int t = threadIdx.x;
  const int w = t >> 6, l = t & 63;
  const int wr = (w >> 1) * 64, wc = (w & 1) * 64;
  const int lr = l & 15;
  const int swr = (lr >> 1) & 3;
  const int arow = (wr + lr) * 64 + (((l >> 4) ^ swr) * 16);
  const int brow = 8192 + (wc + lr) * 64 + (((l >> 4) ^ swr) * 16);
  const int tOff = t * 16;
  {
    char* d = lds + tOff;
    gload_lds16(gA0, d);
    gload_lds16(gA1, d + 4096);
    gload_lds16(gB0, d + 8192);
    gload_lds16(gB1, d + 12288);
  }
  int cur = 0;
  for (int kt = 0; kt < K; kt += 32) {
    const int nxt = kt + 32;
    if (nxt < K) {
      char* d = lds + ((cur ^ 1) << 14) + tOff;
      gload_lds16(gA0 + nxt, d);
      gload_lds16(gA1 + nxt, d + 4096);
      gload_lds16(gB0 + nxt, d + 8192);
      gload_lds16(gB1 + nxt, d + 12288);
      __builtin_amdgcn_sched_barrier(0);
      asm volatile("s_waitcnt vmcnt(4)" ::: "memory");
    } else {
      __builtin_amdgcn_sched_barrier(0);
      asm volatile("s_waitcnt vmcnt(0)" ::: "memory");
    }
    __builtin_amdgcn_sched_barrier(0);
    __builtin_amdgcn_s_barrier();
    __builtin_amdgcn_sched_barrier(0);
    const char* buf = lds + (cur << 14);
    short8 af[4], bfr[4];
#pragma unroll
    for (int f = 0; f < 4; ++f) {
      af[f]  = *(const short8*)(buf + arow + f * 1024);
      bfr[f] = *(const short8*)(buf + brow + f * 1024);
    }
#pragma unroll
    for (int fm = 0; fm < 4; ++fm)
#pragma unroll
      for (int fn = 0; fn < 4; ++fn) {
        if constexpr (F16)
          acc[fm][fn] = __builtin_amdgcn_mfma_f32_16x16x32_f16(
              (h16x8)af[fm], (h16x8)bfr[fn], acc[fm][fn], 0, 0, 0);
        else
          acc[fm][fn] = __builtin_amdgcn_mfma_f32_16x16x32_bf16(af[fm], bfr[fn], acc[fm][fn], 0, 0, 0);
      }
    __builtin_amdgcn_sched_barrier(0);
    __builtin_amdgcn_s_barrier();
    __builtin_amdgcn_sched_barrier(0);
    cur ^= 1;
  }
}

// BK=64 variant, counted vmcnt(8). 64KB LDS. (R14-best for l2.)
__device__ inline void gemm128_db64(const unsigned short* gA0, const unsigned short* gA1,
                                    const unsigned short* gB0, const unsigned short* gB1,
                                    int K, char* lds, f32x4 acc[4][4]) {
  const int t = threadIdx.x;
  const int w = t >> 6, l = t & 63;
  const int wr = (w >> 1) * 64, wc = (w & 1) * 64;
  const int lr = l & 15;
  const int swr = (lr >> 1) & 3;
  const int arow = (wr + lr) * 64 + (((l >> 4) ^ swr) * 16);
  const int brow = 8192 + (wc + lr) * 64 + (((l >> 4) ^ swr) * 16);
  const int tOff = t * 16;
#define STAGE64(bufbase, ksrc) { \
    char* d = lds + (bufbase) + tOff; \
    gload_lds16(gA0 + (ksrc), d); \
    gload_lds16(gA1 + (ksrc), d + 4096); \
    gload_lds16(gB0 + (ksrc), d + 8192); \
    gload_lds16(gB1 + (ksrc), d + 12288); \
    gload_lds16(gA0 + (ksrc) + 32, d + 16384); \
    gload_lds16(gA1 + (ksrc) + 32, d + 16384 + 4096); \
    gload_lds16(gB0 + (ksrc) + 32, d + 16384 + 8192); \
    gload_lds16(gB1 + (ksrc) + 32, d + 16384 + 12288); \
  }
  STAGE64(0, 0);
  int cur = 0;
  for (int kt = 0; kt < K; kt += 64) {
    if (kt + 64 < K) {
      STAGE64((cur ^ 1) << 15, kt + 64);
      __builtin_amdgcn_sched_barrier(0);
      asm volatile("s_waitcnt vmcnt(8)" ::: "memory");
    } else {
      __builtin_amdgcn_sched_barrier(0);
      asm volatile("s_waitcnt vmcnt(0)" ::: "memory");
    }
    __builtin_amdgcn_sched_barrier(0);
    __builtin_amdgcn_s_barrier();
    __builtin_amdgcn_sched_barrier(0);
    const char* buf = lds + (cur << 15);
#pragma unroll
    for (int c = 0; c < 2; ++c) {
      const char* ch = buf + c * 16384;
      short8 af[4], bfr[4];
#pragma unroll
      for (int f = 0; f < 4; ++f) {
        af[f]  = *(const short8*)(ch + arow + f * 1024);
        bfr[f] = *(const short8*)(ch + brow + f * 1024);
      }
#pragma unroll
      for (int fm = 0; fm < 4; ++fm)
#pragma unroll
        for (int fn = 0; fn < 4; ++fn)
          acc[fm][fn] = __builtin_amdgcn_mfma_f32_16x16x32_bf16(af[fm], bfr[fn], acc[fm][fn], 0, 0, 0);
    }
    __builtin_amdgcn_sched_barrier(0);
    __builtin_amdgcn_s_barrier();
    __builtin_amdgcn_sched_barrier(0);
    cur ^= 1;
  }
#undef STAGE64
}

__device__ inline void gemm128_bt64(const unsigned short* __restrict__ A,
                                    const unsigned short* __restrict__ Bm,
                                    int K, char* lds, f32x4 acc[4][4]) {
  const int t = threadIdx.x;
  const int s_orig = (t & 3) ^ ((t >> 3) & 3);
  const size_t srcOff = (size_t)(t >> 2) * K + s_orig * 8;
  gemm128_db64(A + srcOff, A + srcOff + (size_t)64 * K,
               Bm + srcOff, Bm + srcOff + (size_t)64 * K, K, lds, acc);
}

// ---- prep: gather/pad/convert x_reg, W1g; W2 bf16; router fp16 hi/lo splits ----
__global__ void k_prep(const float* __restrict__ x, const float* __restrict__ W1,
                       const float* __restrict__ W2, const int* __restrict__ ig,
                       const float* __restrict__ Wr1,
                       unsigned short* __restrict__ xreg, unsigned short* __restrict__ w1g,
                       unsigned short* __restrict__ w2b,
                       unsigned short* __restrict__ xsp, unsigned short* __restrict__ wr1sp) {
  const size_t N1 = (size_t)4 * B_ * KP;
  const size_t N2 = (size_t)4 * H_ * KP;
  const size_t N3 = (size_t)O_ * H_;
  const size_t N4 = (size_t)B_ * KR;
  const size_t N5 = (size_t)RH_ * KR;
  const size_t TOT = N1 + N2 + N3 + N4 + N5;
  for (size_t idx = (size_t)blockIdx.x * blockDim.x + threadIdx.x; idx < TOT;
       idx += (size_t)gridDim.x * blockDim.x) {
    if (idx < N1) {
      int n = (int)(idx % KP); size_t r = idx / KP;
      int b = (int)(r % B_); int i = (int)(r / B_);
      float v = (n < 196) ? x[(size_t)b * D_ + ig[i * 196 + n]] : 0.f;
      xreg[idx] = f2bf(v);
    } else if (idx < N1 + N2) {
      size_t q = idx - N1;
      int n = (int)(q % KP); size_t r = q / KP;
      int h = (int)(r % H_); int i = (int)(r / H_);
      float v = (n < 196) ? W1[(size_t)h * D_ + ig[i * 196 + n]] : 0.f;
      w1g[q] = f2bf(v);
    } else if (idx < N1 + N2 + N3) {
      size_t q = idx - N1 - N2;
      w2b[q] = f2bf(W2[q]);
    } else if (idx < N1 + N2 + N3 + N4) {
      size_t q = idx - N1 - N2 - N3;
      int c = (int)(q % KR); int b = (int)(q / KR);
      float v = (c < D_) ? x[(size_t)b * D_ + c] : 0.f;
      unsigned short hi = f2h(v);
      unsigned short lo = f2h(v - h2f(hi));
      xsp[(size_t)b * (2 * KR) + c]      = hi;
      xsp[(size_t)b * (2 * KR) + KR + c] = lo;
    } else {
      size_t q = idx - N1 - N2 - N3 - N4;
      int c = (int)(q % KR); int h = (int)(q / KR);
      float v = (c < D_) ? Wr1[(size_t)h * D_ + c] : 0.f;
      unsigned short hi = f2h(v);
      unsigned short lo = f2h(v - h2f(hi));
      wr1sp[(size_t)h * KR + c]                    = hi;  // term 0: hi (vs x_hi)
      wr1sp[(size_t)RH_ * KR + h * KR + c]         = hi;  // term 1: hi (vs x_lo)
      wr1sp[(size_t)2 * RH_ * KR + h * KR + c]     = lo;  // term 2: lo (vs x_hi)
    }
  }
}

// ---- router stage 1: fp16x3 MFMA GEMM. hrp[z][b][h], z = term. grid (64,3) ----
__global__ __launch_bounds__(256) void k_r1m(const unsigned short* __restrict__ xsp,
    const unsigned short* __restrict__ wr1sp, float* __restrict__ hrp) {
  __shared__ __align__(128) char lds[32768];
  const int mt = blockIdx.x, z = blockIdx.y;
  const int t = threadIdx.x;
  const int aoff = (z == 1) ? KR : 0;
  const int s_orig = (t & 3) ^ ((t >> 3) & 3);
  const int scol = s_orig * 8;
  const unsigned short* gA0 = xsp + ((size_t)(mt * 128) + (t >> 2)) * (2 * KR) + aoff + scol;
  const unsigned short* gA1 = gA0 + (size_t)64 * (2 * KR);
  const unsigned short* gB0 = wr1sp + (size_t)z * RH_ * KR + (size_t)(t >> 2) * KR + scol;
  const unsigned short* gB1 = gB0 + (size_t)64 * KR;
  f32x4 acc[4][4];
#pragma unroll
  for (int a = 0; a < 4; ++a)
#pragma unroll
    for (int b = 0; b < 4; ++b) acc[a][b] = (f32x4){0.f, 0.f, 0.f, 0.f};
  gemm128_db<true>(gA0, gA1, gB0, gB1, KR, lds, acc);
  float* hz = hrp + (size_t)z * B_ * RH_;
  const int w = t >> 6, l = t & 63;
  const int rbase = mt * 128 + (w >> 1) * 64 + (l >> 4) * 4;
  const int cb = (w & 1) * 64 + (l & 15);
#pragma unroll
  for (int fn = 0; fn < 4; ++fn) {
    const int h = cb + fn * 16;
#pragma unroll
    for (int fm = 0; fm < 4; ++fm)
#pragma unroll
      for (int r = 0; r < 4; ++r)
        hz[(size_t)(rbase + fm * 16 + r) * RH_ + h] = acc[fm][fn][r];
  }
}

// ---- router stage 2: reduce 3 fp16x3 partials + bias + relu, softmax, top-8 ----
#define R2S 32
__global__ __launch_bounds__(256) void k_r2(const float* __restrict__ hrp,
    const float* __restrict__ br1,
    const float* __restrict__ Wr2, const float* __restrict__ br2,
    float* __restrict__ wts, float* __restrict__ wsum,
    unsigned long long* __restrict__ actmask) {
  __shared__ float Ws[64][130];
  __shared__ float hs[R2S][128];
  const int s0 = blockIdx.x * R2S;
  const int t = threadIdx.x;
  for (int idx = t; idx < 2048; idx += 256) {
    int r = idx >> 5, c = (idx & 31) * 4;
    *(float4*)&Ws[r][c] = *(const float4*)(Wr2 + (size_t)r * RH_ + c);
  }
  for (int idx = t; idx < R2S * 32; idx += 256) {
    int r = idx >> 5, c = (idx & 31) * 4;
    const size_t off = (size_t)(s0 + r) * RH_ + c;
    float4 p0 = *(const float4*)(hrp + off);
    float4 p1 = *(const float4*)(hrp + (size_t)1 * B_ * RH_ + off);
    float4 p2 = *(const float4*)(hrp + (size_t)2 * B_ * RH_ + off);
    float4 bb = *(const float4*)(br1 + c);
    float4 s;
    s.x = fmaxf(p0.x + p1.x + p2.x + bb.x, 0.f);
    s.y = fmaxf(p0.y + p1.y + p2.y + bb.y, 0.f);
    s.z = fmaxf(p0.z + p1.z + p2.z + bb.z, 0.f);
    s.w = fmaxf(p0.w + p1.w + p2.w + bb.w, 0.f);
    *(float4*)&hs[r][c] = s;
  }
  __syncthreads();
  const int w = t >> 6, p = t & 63;
  const float wb2 = br2[p];
  for (int si = 0; si < R2S / 4; ++si) {
    const int sl = w * (R2S / 4) + si;
    float sc = wb2;
#pragma unroll
    for (int kk = 0; kk < 32; ++kk) {
      float4 h4 = *(const float4*)&hs[sl][kk * 4];
      float4 w4 = *(const float4*)&Ws[p][kk * 4];
      sc += h4.x * w4.x + h4.y * w4.y + h4.z * w4.z + h4.w * w4.w;
    }
    float m = sc;
#pragma unroll
    for (int o = 32; o; o >>= 1) m = fmaxf(m, __shfl_xor(m, o));
    float e = __expf(sc - m);
    float Z = e;
#pragma unroll
    for (int o = 32; o; o >>= 1) Z += __shfl_xor(Z, o);
    bool sel = false;
    float ssum = 0.f;
    for (int it = 0; it < 8; ++it) {
      float v = sel ? -1.f : e;
      float vm = v;
#pragma unroll
      for (int o = 32; o; o >>= 1) vm = fmaxf(vm, __shfl_xor(vm, o));
      unsigned long long mask = __ballot(!sel && v == vm);
      int first = __ffsll((long long)mask) - 1;
      if (p == first) sel = true;
      ssum += vm;
    }
    const float dn = 1.0f / (ssum + 1e-8f * Z);
    const float wv = sel ? e * dn : 0.f;
    wts[(size_t)(s0 + sl) * 64 + p] = wv;
    const unsigned long long am = __ballot(sel);
    if (p == 0) actmask[s0 + sl] = am;
    float part = wv;
#pragma unroll
    for (int o = 4; o < 64; o <<= 1) part += __shfl_xor(part, o);
    if (p < 4) wsum[(size_t)(s0 + sl) * 4 + p] = part;
  }
}

// ---- compact: per (i,j), ordered active-sample list. Masks register-prefetched. ----
__global__ __launch_bounds__(256) void k_compact(const unsigned long long* __restrict__ actmask,
                                                 int* __restrict__ lists,
                                                 int* __restrict__ counts) {
  __shared__ int wcnt[4];
  __shared__ int sbase;
  const int ij = blockIdx.x;
  const int shift = (ij >> 2) * 16 + (ij & 3) * 4;
  const int t = threadIdx.x;
  const int wid = t >> 6, lane = t & 63;
  unsigned long long mk[32];
#pragma unroll
  for (int c = 0; c < 32; ++c) mk[c] = actmask[c * 256 + t];
  if (t == 0) sbase = 0;
  __syncthreads();
  for (int c = 0; c < 32; ++c) {
    const int b = c * 256 + t;
    const bool act = ((mk[c] >> shift) & 0xFULL) != 0ULL;
    const unsigned long long m = __ballot(act);
    if (lane == 0) wcnt[wid] = __popcll(m);
    __syncthreads();
    int off = sbase;
    const int tot = wcnt[0] + wcnt[1] + wcnt[2] + wcnt[3];
    for (int q = 0; q < wid; ++q) off += wcnt[q];
    if (act)
      lists[ij * B_ + off + __popcll(m & ((1ULL << lane) - 1ULL))] = b;
    __syncthreads();
    if (t == 0) sbase += tot;
  }
  __syncthreads();
  if (t == 0) counts[ij] = sbase;
}

// ---- layer 1, ONE-SHOT FULL-K STAGE (kept from R19): 112KB LDS holds the
// entire gathered A and B tiles; single vmcnt(0)+barrier; 112 MFMA with no
// further barriers. XCD-clustered mapping (L2-resident). fp16 pre-act out. ----
__global__ __launch_bounds__(256) void k_l1g(const unsigned short* __restrict__ xreg,
    const unsigned short* __restrict__ w1g, const float* __restrict__ b1,
    const int* __restrict__ lists, const int* __restrict__ counts,
    unsigned short* __restrict__ hid16) {
  const int id = blockIdx.x;
  const int xcd = id & 7;
  const int within = id >> 3;          // 0..511
  const int ij = xcd * 2 + (within >> 8);
  const int sub = within & 255;
  const int mt = sub >> 2;
  const int ntl = sub & 3;
  const int iq = ij >> 2;
  const int nt = (ij & 3) * 4 + ntl;
  const int count = counts[ij];
  if (mt * 128 >= count) return;
  __shared__ __align__(128) char lds[114688];   // A 7*8KB | B 7*8KB
  __shared__ int rows[128];
  const int t = threadIdx.x;
  const int* list = lists + (size_t)ij * B_;
  if (t < 128) {
    int rl = mt * 128 + t;
    rows[t] = list[rl < count ? rl : count - 1];
  }
  __syncthreads();
  const int s_orig = (t & 3) ^ ((t >> 3) & 3);
  const int scol = s_orig * 8;
  const int r0 = rows[t >> 2], r1 = rows[(t >> 2) + 64];
  const unsigned short* gA0 = xreg + ((size_t)iq * B_ + r0) * KP + scol;
  const unsigned short* gA1 = xreg + ((size_t)iq * B_ + r1) * KP + scol;
  const unsigned short* gB0 = w1g + ((size_t)(iq * H_ + nt * 128) + (t >> 2)) * KP + scol;
  const unsigned short* gB1 = gB0 + (size_t)64 * KP;
  char* ldsA = lds;
  char* ldsB = lds + 57344;
  const int tOff = t * 16;
#pragma unroll
  for (int ks = 0; ks < 7; ++ks) {
    gload_lds16(gA0 + ks * 32, ldsA + ks * 8192 + tOff);
    gload_lds16(gA1 + ks * 32, ldsA + ks * 8192 + 4096 + tOff);
    gload_lds16(gB0 + ks * 32, ldsB + ks * 8192 + tOff);
    gload_lds16(gB1 + ks * 32, ldsB + ks * 8192 + 4096 + tOff);
  }
  asm volatile("s_waitcnt vmcnt(0)" ::: "memory");
  __builtin_amdgcn_sched_barrier(0);
  __builtin_amdgcn_s_barrier();
  __builtin_amdgcn_sched_barrier(0);
  const int w = t >> 6, l = t & 63;
  const int wr = (w >> 1) * 64, wc = (w & 1) * 64;
  const int lr = l & 15;
  const int swr = (lr >> 1) & 3;
  const int arow = (wr + lr) * 64 + (((l >> 4) ^ swr) * 16);
  const int brow = (wc + lr) * 64 + (((l >> 4) ^ swr) * 16);
  f32x4 acc[4][4];
#pragma unroll
  for (int a = 0; a < 4; ++a)
#pragma unroll
    for (int b = 0; b < 4; ++b) acc[a][b] = (f32x4){0.f, 0.f, 0.f, 0.f};
#pragma unroll
  for (int ks = 0; ks < 7; ++ks) {
    const char* bufA = ldsA + ks * 8192;
    const char* bufB = ldsB + ks * 8192;
    short8 af[4], bfr[4];
#pragma unroll
    for (int f = 0; f < 4; ++f) {
      af[f]  = *(const short8*)(bufA + arow + f * 1024);
      bfr[f] = *(const short8*)(bufB + brow + f * 1024);
    }
#pragma unroll
    for (int fm = 0; fm < 4; ++fm)
#pragma unroll
      for (int fn = 0; fn < 4; ++fn)
        acc[fm][fn] = __builtin_amdgcn_mfma_f32_16x16x32_bf16(af[fm], bfr[fn], acc[fm][fn], 0, 0, 0);
  }
  // epilogue: bias + fp16 pre-act -> LDS repack (16B-granule XOR swizzle) -> vector scatter
  const int rloc0 = (w >> 1) * 64 + (l >> 4) * 4;
  const int cloc = (w & 1) * 64 + (l & 15);
  unsigned short* lt = (unsigned short*)lds;
  __syncthreads();   // all LDS reads done before overwrite
#pragma unroll
  for (int fn = 0; fn < 4; ++fn) {
    const int col = cloc + fn * 16;
    const float bias = b1[nt * 128 + col];
#pragma unroll
    for (int fm = 0; fm < 4; ++fm)
#pragma unroll
      for (int r = 0; r < 4; ++r) {
        const int row = rloc0 + fm * 16 + r;
        const int gsw = (col >> 3) ^ (row & 7);
        lt[row * 128 + gsw * 8 + (col & 7)] = f2h(acc[fm][fn][r] + bias);
      }
  }
  __syncthreads();
  const int mlim = count - mt * 128;
  const int row = t >> 1, half = t & 1;
  if (row < mlim) {
    unsigned short* dst = hid16 + ((size_t)iq * B_ + rows[row]) * H_ + nt * 128 + half * 64;
#pragma unroll
    for (int q = 0; q < 8; ++q) {
      const int g = (half * 8 + q) ^ (row & 7);
      *(short8*)(dst + q * 8) = *(const short8*)(lt + row * 128 + g * 8);
    }
  }
}

// ---- combine: skip zero-weight pathways, gelu here (idle VALU). fp16 -> bf16 G ----
__global__ __launch_bounds__(256) void k_combine(unsigned short* __restrict__ hid,
                                                 const float* __restrict__ wts) {
  const int b = blockIdx.x;
  const int n = threadIdx.x * 8;
  const int j = n >> 9;
  const float* wb = wts + (size_t)b * 64 + j * 4;
  float acc[4][8];
#pragma unroll
  for (int k = 0; k < 4; ++k)
#pragma unroll
    for (int e = 0; e < 8; ++e) acc[k][e] = 0.f;
#pragma unroll
  for (int i = 0; i < 4; ++i) {
    const float4 w4 = *(const float4*)(wb + i * 16);
    if (w4.x != 0.f || w4.y != 0.f || w4.z != 0.f || w4.w != 0.f) {
      short8 raw = *(const short8*)(hid + ((size_t)i * B_ + b) * H_ + n);
#pragma unroll
      for (int e = 0; e < 8; ++e) {
        float g = gelu_exact(h2f((unsigned short)raw[e]));
        acc[0][e] += g * w4.x;
        acc[1][e] += g * w4.y;
        acc[2][e] += g * w4.z;
        acc[3][e] += g * w4.w;
      }
    }
  }
#pragma unroll
  for (int k = 0; k < 4; ++k) {
    short8 outv;
#pragma unroll
    for (int e = 0; e < 8; ++e) outv[e] = (short)f2bf(acc[k][e]);
    *(short8*)(hid + ((size_t)k * B_ + b) * H_ + n) = outv;
  }
}

// ---- layer 2 (R14-best config): BK=64, 64KB LDS, id>>6 panel grouping. ----
__global__ __launch_bounds__(256) void k_l2(const unsigned short* __restrict__ G,
    const unsigned short* __restrict__ w2b, const float* __restrict__ b2,
    const float* __restrict__ wsum, float* __restrict__ out) {
  __shared__ __align__(128) char lds[65536];
  const int id = blockIdx.x;
  const int grp = id >> 6, mt = id & 63;
  const int nt = grp & 1, k = grp >> 1;
  const unsigned short* A  = G + ((size_t)k * B_ + mt * 128) * H_;
  const unsigned short* Bm = w2b + ((size_t)(k * 256 + nt * 128)) * H_;
  f32x4 acc[4][4];
#pragma unroll
  for (int a = 0; a < 4; ++a)
#pragma unroll
    for (int b = 0; b < 4; ++b) acc[a][b] = (f32x4){0.f, 0.f, 0.f, 0.f};
  gemm128_bt64(A, Bm, H_, lds, acc);
  const int t = threadIdx.x, w = t >> 6, l = t & 63;
  const int rbase = mt * 128 + (w >> 1) * 64 + (l >> 4) * 4;
  const int cb = nt * 128 + (w & 1) * 64 + (l & 15);
#pragma unroll
  for (int fn = 0; fn < 4; ++fn) {
    const int ncol = k * 256 + cb + fn * 16;
    const float bias = b2[ncol];
#pragma unroll
    for (int fm = 0; fm < 4; ++fm)
#pragma unroll
      for (int r = 0; r < 4; ++r) {
        const int m = rbase + fm * 16 + r;
        out[(size_t)m * O_ + ncol] = acc[fm][fn][r] + wsum[m * 4 + k] * bias;
      }
  }
}

extern "C" void kernel_launch(void* const* d_in, const int* in_sizes, int n_in,
                              void* d_out, int out_size, void* d_ws, size_t ws_size,
                              hipStream_t stream) {
  const float* x   = (const float*)d_in[0];
  const float* W1  = (const float*)d_in[1];
  const float* b1  = (const float*)d_in[2];
  const float* W2  = (const float*)d_in[3];
  const float* b2  = (const float*)d_in[4];
  const float* Wr1 = (const float*)d_in[5];
  const float* br1 = (const float*)d_in[6];
  const float* Wr2 = (const float*)d_in[7];
  const float* br2 = (const float*)d_in[8];
  const int*   ig  = (const int*)d_in[9];
  float* out = (float*)d_out;
  char* ws = (char*)d_ws;
  unsigned short* xreg = (unsigned short*)(ws);              // 14,680,064 B
  unsigned short* w1g  = (unsigned short*)(ws + 14680064);   //  3,670,016 B
  unsigned short* w2b  = (unsigned short*)(ws + 18350080);   //  4,194,304 B
  float*          wts  = (float*)(ws + 22544384);            //  2,097,152 B
  float*          wsum = (float*)(ws + 24641536);            //    131,072 B
  unsigned short* hid  = (unsigned short*)(ws + 24772608);   // 134,217,728 B (fp16 pre-act, then bf16 G in-place)
  // router-phase scratch aliased onto hid region (all dead before k_l1g writes):
  float*          hrp   = (float*)(ws + 24772608);                 // 12,582,912 B
  unsigned short* xsp   = (unsigned short*)(ws + 24772608 + 12582912);   // 26,214,400 B
  unsigned short* wr1sp = (unsigned short*)(ws + 24772608 + 38797312);   // 614,400 B
  // scratch in d_out (fully overwritten by k_l2's dense writes afterwards):
  int*                lists   = (int*)d_out;                 // 524,288 B
  int*                counts  = lists + 16 * B_;             // 64 B
  unsigned long long* actmask = (unsigned long long*)((char*)d_out + 524352);  // 65,536 B

  k_prep<<<dim3(2048), dim3(256), 0, stream>>>(x, W1, W2, ig, Wr1, xreg, w1g, w2b, xsp, wr1sp);
  k_r1m<<<dim3(B_ / 128, 3), dim3(256), 0, stream>>>(xsp, wr1sp, hrp);
  k_r2<<<dim3(B_ / R2S), dim3(256), 0, stream>>>(hrp, br1, Wr2, br2, wts, wsum, actmask);
  k_compact<<<dim3(16), dim3(256), 0, stream>>>(actmask, lists, counts);
  k_l1g<<<dim3(4096), dim3(256), 0, stream>>>(xreg, w1g, b1, lists, counts, hid);
  k_combine<<<dim3(B_), dim3(256), 0, stream>>>(hid, wts);
  k_l2<<<dim3(512), dim3(256), 0, stream>>>(hid, w2b, b2, wsum, out);
}

// Round 21
// 203.642 us; speedup vs baseline: 1.3930x; 1.0787x over previous
//
#include <hip/hip_runtime.h>
#include <hip/hip_bf16.h>
#include <hip/hip_fp16.h>

#define B_  8192
#define D_  784
#define H_  2048
#define O_  1024
#define RH_ 128
#define P_  64
#define KP  224   // 196 padded to 7*32
#define KR  800   // router K: 784 padded to 25*32

typedef __attribute__((ext_vector_type(8))) short short8;
typedef __attribute__((ext_vector_type(8))) _Float16 h16x8;
typedef __attribute__((ext_vector_type(4))) float f32x4;

__device__ inline float bf2f(unsigned short u) {
  union { unsigned int i; float f; } v; v.i = ((unsigned int)u) << 16; return v.f;
}
__device__ inline unsigned short f2bf(float f) {
  __hip_bfloat16 h = __float2bfloat16(f);
  return *reinterpret_cast<unsigned short*>(&h);
}
__device__ inline unsigned short f2h(float f) {
  __half h = __float2half(f);
  return *reinterpret_cast<unsigned short*>(&h);
}
__device__ inline float h2f(unsigned short u) {
  __half h = *reinterpret_cast<__half*>(&u);
  return __half2float(h);
}
// Abramowitz-Stegun 7.1.26, max abs err ~1.5e-7
__device__ inline float erf_fast(float x) {
  float ax = fabsf(x);
  float t = 1.0f / (1.0f + 0.3275911f * ax);
  float p = ((((1.061405429f * t - 1.453152027f) * t + 1.421413741f) * t
              - 0.284496736f) * t + 0.254829592f) * t;
  float y = 1.0f - p * __expf(-ax * ax);
  return x < 0.f ? -y : y;
}
__device__ inline float gelu_exact(float v) {
  return 0.5f * v * (1.0f + erf_fast(v * 0.70710678118654752f));
}

__device__ inline void gload_lds16(const void* g, void* l) {
  __builtin_amdgcn_global_load_lds((const __attribute__((address_space(1))) void*)g,
                                   (__attribute__((address_space(3))) void*)l, 16, 0, 0);
}

// 128x128xK MFMA tile, double-buffered, counted-vmcnt (T4). 32KB LDS.
// T2 source-preswizzle (conflict-free, verified R3-R20: SQ_LDS_BANK_CONFLICT==0).
template <bool F16>
__device__ inline void gemm128_db(const unsigned short* gA0, const unsigned short* gA1,
                                  const unsigned short* gB0, const unsigned short* gB1,
                                  int K, char* lds, f32x4 acc[4][4]) {
  const int t = threadIdx.x;
  const int w = t >> 6, l = t & 63;
  const int wr = (w >> 1) * 64, wc = (w & 1) * 64;
  const int lr = l & 15;
  const int swr = (lr >> 1) & 3;
  const int arow = (wr + lr) * 64 + (((l >> 4) ^ swr) * 16);
  const int brow = 8192 + (wc + lr) * 64 + (((l >> 4) ^ swr) * 16);
  const int tOff = t * 16;
  {
    char* d = lds + tOff;
    gload_lds16(gA0, d);
    gload_lds16(gA1, d + 4096);
    gload_lds16(gB0, d + 8192);
    gload_lds16(gB1, d + 12288);
  }
  int cur = 0;
  for (int kt = 0; kt < K; kt += 32) {
    const int nxt = kt + 32;
    if (nxt < K) {
      char* d = lds + ((cur ^ 1) << 14) + tOff;
      gload_lds16(gA0 + nxt, d);
      gload_lds16(gA1 + nxt, d + 4096);
      gload_lds16(gB0 + nxt, d + 8192);
      gload_lds16(gB1 + nxt, d + 12288);
      __builtin_amdgcn_sched_barrier(0);
      asm volatile("s_waitcnt vmcnt(4)" ::: "memory");
    } else {
      __builtin_amdgcn_sched_barrier(0);
      asm volatile("s_waitcnt vmcnt(0)" ::: "memory");
    }
    __builtin_amdgcn_sched_barrier(0);
    __builtin_amdgcn_s_barrier();
    __builtin_amdgcn_sched_barrier(0);
    const char* buf = lds + (cur << 14);
    short8 af[4], bfr[4];
#pragma unroll
    for (int f = 0; f < 4; ++f) {
      af[f]  = *(const short8*)(buf + arow + f * 1024);
      bfr[f] = *(const short8*)(buf + brow + f * 1024);
    }
#pragma unroll
    for (int fm = 0; fm < 4; ++fm)
#pragma unroll
      for (int fn = 0; fn < 4; ++fn) {
        if constexpr (F16)
          acc[fm][fn] = __builtin_amdgcn_mfma_f32_16x16x32_f16(
              (h16x8)af[fm], (h16x8)bfr[fn], acc[fm][fn], 0, 0, 0);
        else
          acc[fm][fn] = __builtin_amdgcn_mfma_f32_16x16x32_bf16(af[fm], bfr[fn], acc[fm][fn], 0, 0, 0);
      }
    __builtin_amdgcn_sched_barrier(0);
    __builtin_amdgcn_s_barrier();
    __builtin_amdgcn_sched_barrier(0);
    cur ^= 1;
  }
}

// BK=64 variant, counted vmcnt(8). 64KB LDS. (R14-best for l2.)
__device__ inline void gemm128_db64(const unsigned short* gA0, const unsigned short* gA1,
                                    const unsigned short* gB0, const unsigned short* gB1,
                                    int K, char* lds, f32x4 acc[4][4]) {
  const int t = threadIdx.x;
  const int w = t >> 6, l = t & 63;
  const int wr = (w >> 1) * 64, wc = (w & 1) * 64;
  const int lr = l & 15;
  const int swr = (lr >> 1) & 3;
  const int arow = (wr + lr) * 64 + (((l >> 4) ^ swr) * 16);
  const int brow = 8192 + (wc + lr) * 64 + (((l >> 4) ^ swr) * 16);
  const int tOff = t * 16;
#define STAGE64(bufbase, ksrc) { \
    char* d = lds + (bufbase) + tOff; \
    gload_lds16(gA0 + (ksrc), d); \
    gload_lds16(gA1 + (ksrc), d + 4096); \
    gload_lds16(gB0 + (ksrc), d + 8192); \
    gload_lds16(gB1 + (ksrc), d + 12288); \
    gload_lds16(gA0 + (ksrc) + 32, d + 16384); \
    gload_lds16(gA1 + (ksrc) + 32, d + 16384 + 4096); \
    gload_lds16(gB0 + (ksrc) + 32, d + 16384 + 8192); \
    gload_lds16(gB1 + (ksrc) + 32, d + 16384 + 12288); \
  }
  STAGE64(0, 0);
  int cur = 0;
  for (int kt = 0; kt < K; kt += 64) {
    if (kt + 64 < K) {
      STAGE64((cur ^ 1) << 15, kt + 64);
      __builtin_amdgcn_sched_barrier(0);
      asm volatile("s_waitcnt vmcnt(8)" ::: "memory");
    } else {
      __builtin_amdgcn_sched_barrier(0);
      asm volatile("s_waitcnt vmcnt(0)" ::: "memory");
    }
    __builtin_amdgcn_sched_barrier(0);
    __builtin_amdgcn_s_barrier();
    __builtin_amdgcn_sched_barrier(0);
    const char* buf = lds + (cur << 15);
#pragma unroll
    for (int c = 0; c < 2; ++c) {
      const char* ch = buf + c * 16384;
      short8 af[4], bfr[4];
#pragma unroll
      for (int f = 0; f < 4; ++f) {
        af[f]  = *(const short8*)(ch + arow + f * 1024);
        bfr[f] = *(const short8*)(ch + brow + f * 1024);
      }
#pragma unroll
      for (int fm = 0; fm < 4; ++fm)
#pragma unroll
        for (int fn = 0; fn < 4; ++fn)
          acc[fm][fn] = __builtin_amdgcn_mfma_f32_16x16x32_bf16(af[fm], bfr[fn], acc[fm][fn], 0, 0, 0);
    }
    __builtin_amdgcn_sched_barrier(0);
    __builtin_amdgcn_s_barrier();
    __builtin_amdgcn_sched_barrier(0);
    cur ^= 1;
  }
#undef STAGE64
}

__device__ inline void gemm128_bt64(const unsigned short* __restrict__ A,
                                    const unsigned short* __restrict__ Bm,
                                    int K, char* lds, f32x4 acc[4][4]) {
  const int t = threadIdx.x;
  const int s_orig = (t & 3) ^ ((t >> 3) & 3);
  const size_t srcOff = (size_t)(t >> 2) * K + s_orig * 8;
  gemm128_db64(A + srcOff, A + srcOff + (size_t)64 * K,
               Bm + srcOff, Bm + srcOff + (size_t)64 * K, K, lds, acc);
}

// ---- prep: gather/pad/convert x_reg, W1g; W2 bf16; router fp16 hi/lo splits ----
__global__ void k_prep(const float* __restrict__ x, const float* __restrict__ W1,
                       const float* __restrict__ W2, const int* __restrict__ ig,
                       const float* __restrict__ Wr1,
                       unsigned short* __restrict__ xreg, unsigned short* __restrict__ w1g,
                       unsigned short* __restrict__ w2b,
                       unsigned short* __restrict__ xsp, unsigned short* __restrict__ wr1sp) {
  const size_t N1 = (size_t)4 * B_ * KP;
  const size_t N2 = (size_t)4 * H_ * KP;
  const size_t N3 = (size_t)O_ * H_;
  const size_t N4 = (size_t)B_ * KR;
  const size_t N5 = (size_t)RH_ * KR;
  const size_t TOT = N1 + N2 + N3 + N4 + N5;
  for (size_t idx = (size_t)blockIdx.x * blockDim.x + threadIdx.x; idx < TOT;
       idx += (size_t)gridDim.x * blockDim.x) {
    if (idx < N1) {
      int n = (int)(idx % KP); size_t r = idx / KP;
      int b = (int)(r % B_); int i = (int)(r / B_);
      float v = (n < 196) ? x[(size_t)b * D_ + ig[i * 196 + n]] : 0.f;
      xreg[idx] = f2bf(v);
    } else if (idx < N1 + N2) {
      size_t q = idx - N1;
      int n = (int)(q % KP); size_t r = q / KP;
      int h = (int)(r % H_); int i = (int)(r / H_);
      float v = (n < 196) ? W1[(size_t)h * D_ + ig[i * 196 + n]] : 0.f;
      w1g[q] = f2bf(v);
    } else if (idx < N1 + N2 + N3) {
      size_t q = idx - N1 - N2;
      w2b[q] = f2bf(W2[q]);
    } else if (idx < N1 + N2 + N3 + N4) {
      size_t q = idx - N1 - N2 - N3;
      int c = (int)(q % KR); int b = (int)(q / KR);
      float v = (c < D_) ? x[(size_t)b * D_ + c] : 0.f;
      unsigned short hi = f2h(v);
      unsigned short lo = f2h(v - h2f(hi));
      xsp[(size_t)b * (2 * KR) + c]      = hi;
      xsp[(size_t)b * (2 * KR) + KR + c] = lo;
    } else {
      size_t q = idx - N1 - N2 - N3 - N4;
      int c = (int)(q % KR); int h = (int)(q / KR);
      float v = (c < D_) ? Wr1[(size_t)h * D_ + c] : 0.f;
      unsigned short hi = f2h(v);
      unsigned short lo = f2h(v - h2f(hi));
      wr1sp[(size_t)h * KR + c]                    = hi;  // term 0: hi (vs x_hi)
      wr1sp[(size_t)RH_ * KR + h * KR + c]         = hi;  // term 1: hi (vs x_lo)
      wr1sp[(size_t)2 * RH_ * KR + h * KR + c]     = lo;  // term 2: lo (vs x_hi)
    }
  }
}

// ---- router stage 1: fp16x3 MFMA GEMM. hrp[z][b][h], z = term. grid (64,3) ----
__global__ __launch_bounds__(256) void k_r1m(const unsigned short* __restrict__ xsp,
    const unsigned short* __restrict__ wr1sp, float* __restrict__ hrp) {
  __shared__ __align__(128) char lds[32768];
  const int mt = blockIdx.x, z = blockIdx.y;
  const int t = threadIdx.x;
  const int aoff = (z == 1) ? KR : 0;
  const int s_orig = (t & 3) ^ ((t >> 3) & 3);
  const int scol = s_orig * 8;
  const unsigned short* gA0 = xsp + ((size_t)(mt * 128) + (t >> 2)) * (2 * KR) + aoff + scol;
  const unsigned short* gA1 = gA0 + (size_t)64 * (2 * KR);
  const unsigned short* gB0 = wr1sp + (size_t)z * RH_ * KR + (size_t)(t >> 2) * KR + scol;
  const unsigned short* gB1 = gB0 + (size_t)64 * KR;
  f32x4 acc[4][4];
#pragma unroll
  for (int a = 0; a < 4; ++a)
#pragma unroll
    for (int b = 0; b < 4; ++b) acc[a][b] = (f32x4){0.f, 0.f, 0.f, 0.f};
  gemm128_db<true>(gA0, gA1, gB0, gB1, KR, lds, acc);
  float* hz = hrp + (size_t)z * B_ * RH_;
  const int w = t >> 6, l = t & 63;
  const int rbase = mt * 128 + (w >> 1) * 64 + (l >> 4) * 4;
  const int cb = (w & 1) * 64 + (l & 15);
#pragma unroll
  for (int fn = 0; fn < 4; ++fn) {
    const int h = cb + fn * 16;
#pragma unroll
    for (int fm = 0; fm < 4; ++fm)
#pragma unroll
      for (int r = 0; r < 4; ++r)
        hz[(size_t)(rbase + fm * 16 + r) * RH_ + h] = acc[fm][fn][r];
  }
}

// ---- router stage 2: reduce 3 fp16x3 partials + bias + relu, softmax, top-8 ----
#define R2S 32
__global__ __launch_bounds__(256) void k_r2(const float* __restrict__ hrp,
    const float* __restrict__ br1,
    const float* __restrict__ Wr2, const float* __restrict__ br2,
    float* __restrict__ wts, float* __restrict__ wsum,
    unsigned long long* __restrict__ actmask) {
  __shared__ float Ws[64][130];
  __shared__ float hs[R2S][128];
  const int s0 = blockIdx.x * R2S;
  const int t = threadIdx.x;
  for (int idx = t; idx < 2048; idx += 256) {
    int r = idx >> 5, c = (idx & 31) * 4;
    *(float4*)&Ws[r][c] = *(const float4*)(Wr2 + (size_t)r * RH_ + c);
  }
  for (int idx = t; idx < R2S * 32; idx += 256) {
    int r = idx >> 5, c = (idx & 31) * 4;
    const size_t off = (size_t)(s0 + r) * RH_ + c;
    float4 p0 = *(const float4*)(hrp + off);
    float4 p1 = *(const float4*)(hrp + (size_t)1 * B_ * RH_ + off);
    float4 p2 = *(const float4*)(hrp + (size_t)2 * B_ * RH_ + off);
    float4 bb = *(const float4*)(br1 + c);
    float4 s;
    s.x = fmaxf(p0.x + p1.x + p2.x + bb.x, 0.f);
    s.y = fmaxf(p0.y + p1.y + p2.y + bb.y, 0.f);
    s.z = fmaxf(p0.z + p1.z + p2.z + bb.z, 0.f);
    s.w = fmaxf(p0.w + p1.w + p2.w + bb.w, 0.f);
    *(float4*)&hs[r][c] = s;
  }
  __syncthreads();
  const int w = t >> 6, p = t & 63;
  const float wb2 = br2[p];
  for (int si = 0; si < R2S / 4; ++si) {
    const int sl = w * (R2S / 4) + si;
    float sc = wb2;
#pragma unroll
    for (int kk = 0; kk < 32; ++kk) {
      float4 h4 = *(const float4*)&hs[sl][kk * 4];
      float4 w4 = *(const float4*)&Ws[p][kk * 4];
      sc += h4.x * w4.x + h4.y * w4.y + h4.z * w4.z + h4.w * w4.w;
    }
    float m = sc;
#pragma unroll
    for (int o = 32; o; o >>= 1) m = fmaxf(m, __shfl_xor(m, o));
    float e = __expf(sc - m);
    float Z = e;
#pragma unroll
    for (int o = 32; o; o >>= 1) Z += __shfl_xor(Z, o);
    bool sel = false;
    float ssum = 0.f;
    for (int it = 0; it < 8; ++it) {
      float v = sel ? -1.f : e;
      float vm = v;
#pragma unroll
      for (int o = 32; o; o >>= 1) vm = fmaxf(vm, __shfl_xor(vm, o));
      unsigned long long mask = __ballot(!sel && v == vm);
      int first = __ffsll((long long)mask) - 1;
      if (p == first) sel = true;
      ssum += vm;
    }
    const float dn = 1.0f / (ssum + 1e-8f * Z);
    const float wv = sel ? e * dn : 0.f;
    wts[(size_t)(s0 + sl) * 64 + p] = wv;
    const unsigned long long am = __ballot(sel);
    if (p == 0) actmask[s0 + sl] = am;
    float part = wv;
#pragma unroll
    for (int o = 4; o < 64; o <<= 1) part += __shfl_xor(part, o);
    if (p < 4) wsum[(size_t)(s0 + sl) * 4 + p] = part;
  }
}

// ---- compact: per (i,j), ordered active-sample list. Masks register-prefetched. ----
__global__ __launch_bounds__(256) void k_compact(const unsigned long long* __restrict__ actmask,
                                                 int* __restrict__ lists,
                                                 int* __restrict__ counts) {
  __shared__ int wcnt[4];
  __shared__ int sbase;
  const int ij = blockIdx.x;
  const int shift = (ij >> 2) * 16 + (ij & 3) * 4;
  const int t = threadIdx.x;
  const int wid = t >> 6, lane = t & 63;
  unsigned long long mk[32];
#pragma unroll
  for (int c = 0; c < 32; ++c) mk[c] = actmask[c * 256 + t];
  if (t == 0) sbase = 0;
  __syncthreads();
  for (int c = 0; c < 32; ++c) {
    const int b = c * 256 + t;
    const bool act = ((mk[c] >> shift) & 0xFULL) != 0ULL;
    const unsigned long long m = __ballot(act);
    if (lane == 0) wcnt[wid] = __popcll(m);
    __syncthreads();
    int off = sbase;
    const int tot = wcnt[0] + wcnt[1] + wcnt[2] + wcnt[3];
    for (int q = 0; q < wid; ++q) off += wcnt[q];
    if (act)
      lists[ij * B_ + off + __popcll(m & ((1ULL << lane) - 1ULL))] = b;
    __syncthreads();
    if (t == 0) sbase += tot;
  }
  __syncthreads();
  if (t == 0) counts[ij] = sbase;
}

// ---- layer 1, gathered rows, fp16 pre-act, XCD-clustered (round-robin-aware).
// db-pipelined (R18-best: 47.4us; one-shot full-K staging regressed to 64us). ----
__global__ __launch_bounds__(256) void k_l1g(const unsigned short* __restrict__ xreg,
    const unsigned short* __restrict__ w1g, const float* __restrict__ b1,
    const int* __restrict__ lists, const int* __restrict__ counts,
    unsigned short* __restrict__ hid16) {
  const int id = blockIdx.x;
  const int xcd = id & 7;
  const int within = id >> 3;          // 0..511
  const int ij = xcd * 2 + (within >> 8);
  const int sub = within & 255;
  const int mt = sub >> 2;
  const int ntl = sub & 3;
  const int iq = ij >> 2;
  const int nt = (ij & 3) * 4 + ntl;
  const int count = counts[ij];
  if (mt * 128 >= count) return;
  __shared__ __align__(128) char lds[32768];
  __shared__ int rows[128];
  const int t = threadIdx.x;
  const int* list = lists + (size_t)ij * B_;
  if (t < 128) {
    int rl = mt * 128 + t;
    rows[t] = list[rl < count ? rl : count - 1];
  }
  __syncthreads();
  const int s_orig = (t & 3) ^ ((t >> 3) & 3);
  const int scol = s_orig * 8;
  const int r0 = rows[t >> 2], r1 = rows[(t >> 2) + 64];
  const unsigned short* gA0 = xreg + ((size_t)iq * B_ + r0) * KP + scol;
  const unsigned short* gA1 = xreg + ((size_t)iq * B_ + r1) * KP + scol;
  const unsigned short* gB0 = w1g + ((size_t)(iq * H_ + nt * 128) + (t >> 2)) * KP + scol;
  const unsigned short* gB1 = gB0 + (size_t)64 * KP;
  f32x4 acc[4][4];
#pragma unroll
  for (int a = 0; a < 4; ++a)
#pragma unroll
    for (int b = 0; b < 4; ++b) acc[a][b] = (f32x4){0.f, 0.f, 0.f, 0.f};
  gemm128_db<false>(gA0, gA1, gB0, gB1, KP, lds, acc);
  // epilogue: bias + fp16 pre-act -> LDS tile (16B-granule XOR swizzle) -> vector scatter
  const int w = t >> 6, l = t & 63;
  const int rloc0 = (w >> 1) * 64 + (l >> 4) * 4;
  const int cloc = (w & 1) * 64 + (l & 15);
  unsigned short* lt = (unsigned short*)lds;
  __syncthreads();
#pragma unroll
  for (int fn = 0; fn < 4; ++fn) {
    const int col = cloc + fn * 16;
    const float bias = b1[nt * 128 + col];
#pragma unroll
    for (int fm = 0; fm < 4; ++fm)
#pragma unroll
      for (int r = 0; r < 4; ++r) {
        const int row = rloc0 + fm * 16 + r;
        const int gsw = (col >> 3) ^ (row & 7);
        lt[row * 128 + gsw * 8 + (col & 7)] = f2h(acc[fm][fn][r] + bias);
      }
  }
  __syncthreads();
  const int mlim = count - mt * 128;
  const int row = t >> 1, half = t & 1;
  if (row < mlim) {
    unsigned short* dst = hid16 + ((size_t)iq * B_ + rows[row]) * H_ + nt * 128 + half * 64;
#pragma unroll
    for (int q = 0; q < 8; ++q) {
      const int g = (half * 8 + q) ^ (row & 7);
      *(short8*)(dst + q * 8) = *(const short8*)(lt + row * 128 + g * 8);
    }
  }
}

// ---- combine: skip zero-weight pathways, gelu here (idle VALU). fp16 -> bf16 G ----
__global__ __launch_bounds__(256) void k_combine(unsigned short* __restrict__ hid,
                                                 const float* __restrict__ wts) {
  const int b = blockIdx.x;
  const int n = threadIdx.x * 8;
  const int j = n >> 9;
  const float* wb = wts + (size_t)b * 64 + j * 4;
  float acc[4][8];
#pragma unroll
  for (int k = 0; k < 4; ++k)
#pragma unroll
    for (int e = 0; e < 8; ++e) acc[k][e] = 0.f;
#pragma unroll
  for (int i = 0; i < 4; ++i) {
    const float4 w4 = *(const float4*)(wb + i * 16);
    if (w4.x != 0.f || w4.y != 0.f || w4.z != 0.f || w4.w != 0.f) {
      short8 raw = *(const short8*)(hid + ((size_t)i * B_ + b) * H_ + n);
#pragma unroll
      for (int e = 0; e < 8; ++e) {
        float g = gelu_exact(h2f((unsigned short)raw[e]));
        acc[0][e] += g * w4.x;
        acc[1][e] += g * w4.y;
        acc[2][e] += g * w4.z;
        acc[3][e] += g * w4.w;
      }
    }
  }
#pragma unroll
  for (int k = 0; k < 4; ++k) {
    short8 outv;
#pragma unroll
    for (int e = 0; e < 8; ++e) outv[e] = (short)f2bf(acc[k][e]);
    *(short8*)(hid + ((size_t)k * B_ + b) * H_ + n) = outv;
  }
}

// ---- layer 2 (R14-best config): BK=64, 64KB LDS, id>>6 panel grouping. ----
__global__ __launch_bounds__(256) void k_l2(const unsigned short* __restrict__ G,
    const unsigned short* __restrict__ w2b, const float* __restrict__ b2,
    const float* __restrict__ wsum, float* __restrict__ out) {
  __shared__ __align__(128) char lds[65536];
  const int id = blockIdx.x;
  const int grp = id >> 6, mt = id & 63;
  const int nt = grp & 1, k = grp >> 1;
  const unsigned short* A  = G + ((size_t)k * B_ + mt * 128) * H_;
  const unsigned short* Bm = w2b + ((size_t)(k * 256 + nt * 128)) * H_;
  f32x4 acc[4][4];
#pragma unroll
  for (int a = 0; a < 4; ++a)
#pragma unroll
    for (int b = 0; b < 4; ++b) acc[a][b] = (f32x4){0.f, 0.f, 0.f, 0.f};
  gemm128_bt64(A, Bm, H_, lds, acc);
  const int t = threadIdx.x, w = t >> 6, l = t & 63;
  const int rbase = mt * 128 + (w >> 1) * 64 + (l >> 4) * 4;
  const int cb = nt * 128 + (w & 1) * 64 + (l & 15);
#pragma unroll
  for (int fn = 0; fn < 4; ++fn) {
    const int ncol = k * 256 + cb + fn * 16;
    const float bias = b2[ncol];
#pragma unroll
    for (int fm = 0; fm < 4; ++fm)
#pragma unroll
      for (int r = 0; r < 4; ++r) {
        const int m = rbase + fm * 16 + r;
        out[(size_t)m * O_ + ncol] = acc[fm][fn][r] + wsum[m * 4 + k] * bias;
      }
  }
}

extern "C" void kernel_launch(void* const* d_in, const int* in_sizes, int n_in,
                              void* d_out, int out_size, void* d_ws, size_t ws_size,
                              hipStream_t stream) {
  const float* x   = (const float*)d_in[0];
  const float* W1  = (const float*)d_in[1];
  const float* b1  = (const float*)d_in[2];
  const float* W2  = (const float*)d_in[3];
  const float* b2  = (const float*)d_in[4];
  const float* Wr1 = (const float*)d_in[5];
  const float* br1 = (const float*)d_in[6];
  const float* Wr2 = (const float*)d_in[7];
  const float* br2 = (const float*)d_in[8];
  const int*   ig  = (const int*)d_in[9];
  float* out = (float*)d_out;
  char* ws = (char*)d_ws;
  unsigned short* xreg = (unsigned short*)(ws);              // 14,680,064 B
  unsigned short* w1g  = (unsigned short*)(ws + 14680064);   //  3,670,016 B
  unsigned short* w2b  = (unsigned short*)(ws + 18350080);   //  4,194,304 B
  float*          wts  = (float*)(ws + 22544384);            //  2,097,152 B
  float*          wsum = (float*)(ws + 24641536);            //    131,072 B
  unsigned short* hid  = (unsigned short*)(ws + 24772608);   // 134,217,728 B (fp16 pre-act, then bf16 G in-place)
  // router-phase scratch aliased onto hid region (all dead before k_l1g writes):
  float*          hrp   = (float*)(ws + 24772608);                 // 12,582,912 B
  unsigned short* xsp   = (unsigned short*)(ws + 24772608 + 12582912);   // 26,214,400 B
  unsigned short* wr1sp = (unsigned short*)(ws + 24772608 + 38797312);   // 614,400 B
  // scratch in d_out (fully overwritten by k_l2's dense writes afterwards):
  int*                lists   = (int*)d_out;                 // 524,288 B
  int*                counts  = lists + 16 * B_;             // 64 B
  unsigned long long* actmask = (unsigned long long*)((char*)d_out + 524352);  // 65,536 B

  k_prep<<<dim3(2048), dim3(256), 0, stream>>>(x, W1, W2, ig, Wr1, xreg, w1g, w2b, xsp, wr1sp);
  k_r1m<<<dim3(B_ / 128, 3), dim3(256), 0, stream>>>(xsp, wr1sp, hrp);
  k_r2<<<dim3(B_ / R2S), dim3(256), 0, stream>>>(hrp, br1, Wr2, br2, wts, wsum, actmask);
  k_compact<<<dim3(16), dim3(256), 0, stream>>>(actmask, lists, counts);
  k_l1g<<<dim3(4096), dim3(256), 0, stream>>>(xreg, w1g, b1, lists, counts, hid);
  k_combine<<<dim3(B_), dim3(256), 0, stream>>>(hid, wts);
  k_l2<<<dim3(512), dim3(256), 0, stream>>>(hid, w2b, b2, wsum, out);
}